// Round 19
// baseline (319.236 us; speedup 1.0000x reference)
//
#include <hip/hip_runtime.h>
#include <hip/hip_fp16.h>

// B=8192, T=512, IN=1, H=20, OUT=1
#define B_TOTAL 8192
#define T_LEN   512
#define H       20
#define XSTR    516            // xs row stride (floats): 2-way bank alias max (free)

typedef _Float16 f16x4 __attribute__((ext_vector_type(4)));
typedef float    f32x4 __attribute__((ext_vector_type(4)));
typedef unsigned int u32;

// 16x16x16 f16 MFMA (R18-validated): D lane(b,g) rows j=4g+r ; B lane(b,g)
// k=4g+i -> tanh(D)+pack IS next step's B-fragment, zero cross-lane ops.
#if defined(__HIP_DEVICE_COMPILE__)
  #if __has_builtin(__builtin_amdgcn_mfma_f32_16x16x16_f16)
    #define MFMA16(a, b, c) __builtin_amdgcn_mfma_f32_16x16x16_f16((a), (b), (c), 0, 0, 0)
  #elif __has_builtin(__builtin_amdgcn_mfma_f32_16x16x16f16)
    #define MFMA16(a, b, c) __builtin_amdgcn_mfma_f32_16x16x16f16((a), (b), (c), 0, 0, 0)
  #else
    #error "no 16x16x16 f16 MFMA builtin on device"
  #endif
#else
  #define MFMA16(a, b, c) (c)   // host parse stub
#endif

__device__ __forceinline__ float fast_tanh(float x) {
    float e = __builtin_amdgcn_exp2f(x * 2.885390081777927f);
    return fmaf(-2.0f, __builtin_amdgcn_rcpf(e + 1.0f), 1.0f);
}
__device__ __forceinline__ u32 pk2(float a, float b) {
    return __builtin_bit_cast(u32, __builtin_amdgcn_cvt_pkrtz(a, b));
}
__device__ __forceinline__ f16x4 u2f(uint2 v) { return __builtin_bit_cast(f16x4, v); }

// ---- prologue: pack 5 HxH matrices into 16x16x16 A-fragments (R18, verbatim) ----
__global__ void prep_w(const float* __restrict__ w_hh0, const float* __restrict__ w_ih1,
                       const float* __restrict__ w_hh1, const float* __restrict__ w_ih2,
                       const float* __restrict__ w_hh2, u32* __restrict__ ws)
{
    for (int e = threadIdx.x; e < 5 * 4 * 64; e += 256) {
        int l = e & 63, f = (e >> 6) & 3, m = e >> 8;
        const float* src = (m == 0) ? w_hh0 : (m == 1) ? w_ih1 :
                           (m == 2) ? w_hh1 : (m == 3) ? w_ih2 : w_hh2;
        int p = l & 15, g = l >> 4;
        int row = (f & 2) ? 16 + p : p;
        int kb  = ((f & 1) ? 16 : 0) + 4 * g;
        u32 d0 = 0, d1 = 0;
        if (row < H) {
            unsigned short h[4];
            #pragma unroll
            for (int i = 0; i < 4; ++i) {
                int k = kb + i;
                _Float16 v = (k < H) ? (_Float16)src[row * H + k] : (_Float16)0.f;
                h[i] = __builtin_bit_cast(unsigned short, v);
            }
            d0 = (u32)h[0] | ((u32)h[1] << 16);
            d1 = (u32)h[2] | ((u32)h[3] << 16);
        }
        ws[e * 2 + 0] = d0;
        ws[e * 2 + 1] = d1;
    }
}

#define LDF(name, m, f) \
    const f16x4 name = u2f(*(const uint2*)(wpk + (((m) * 4 + (f)) * 64 + l) * 2));

// tanh(D1,D2) -> packed f16 state (lo = k 4g..4g+3, hi = k 16..19 on g==0)
#define TANHPK(lo, hi, D1, D2) { \
    u32 a0 = pk2(fast_tanh((D1)[0]), fast_tanh((D1)[1])); \
    u32 a1 = pk2(fast_tanh((D1)[2]), fast_tanh((D1)[3])); \
    u32 a2 = pk2(fast_tanh((D2)[0]), fast_tanh((D2)[1])); \
    u32 a3 = pk2(fast_tanh((D2)[2]), fast_tanh((D2)[3])); \
    lo = u2f(make_uint2(a0, a1)); \
    hi = u2f(make_uint2(a2, a3)); \
}

// One diagonal-pipeline tick: h0(s)[DO0], h1(s-1)[DO1], h2(s-2)[DO2].
// All reads use pre-commit register values; single wave, no barriers, no LDS h.
// Input/recurrent accumulators split -> two 2-deep MFMA chains + vector add.
#define TICK(sidx, DO0, DO1, DO2) { \
    f16x4 n0lo = H0lo, n0hi = H0hi, n1lo = H1lo, n1hi = H1hi, n2lo = H2lo, n2hi = H2hi; \
    if (DO0) { \
        float xv = xs[b][(sidx)]; \
        f32x4 P1, P2; \
        _Pragma("unroll") \
        for (int r = 0; r < 4; ++r) { \
            P1[r] = fmaf(xv, w0lo[r], bd01[r]); \
            P2[r] = fmaf(xv, w0hi[r], bd02[r]); \
        } \
        f32x4 D1 = MFMA16(W0f0, H0lo, P1); D1 = MFMA16(W0f1, H0hi, D1); \
        f32x4 D2 = MFMA16(W0f2, H0lo, P2); D2 = MFMA16(W0f3, H0hi, D2); \
        TANHPK(n0lo, n0hi, D1, D2) \
    } \
    if (DO1) { \
        f32x4 A1 = MFMA16(W1f0, H0lo, bd11); A1 = MFMA16(W1f1, H0hi, A1); \
        f32x4 R1 = MFMA16(W2f0, H1lo, Z);    R1 = MFMA16(W2f1, H1hi, R1); \
        f32x4 A2 = MFMA16(W1f2, H0lo, bd12); A2 = MFMA16(W1f3, H0hi, A2); \
        f32x4 R2 = MFMA16(W2f2, H1lo, Z);    R2 = MFMA16(W2f3, H1hi, R2); \
        f32x4 D1 = A1 + R1, D2 = A2 + R2; \
        TANHPK(n1lo, n1hi, D1, D2) \
    } \
    if (DO2) { \
        f32x4 A1 = MFMA16(W3f0, H1lo, bd21); A1 = MFMA16(W3f1, H1hi, A1); \
        f32x4 R1 = MFMA16(W4f0, H2lo, Z);    R1 = MFMA16(W4f1, H2hi, R1); \
        f32x4 A2 = MFMA16(W3f2, H1lo, bd22); A2 = MFMA16(W3f3, H1hi, A2); \
        f32x4 R2 = MFMA16(W4f2, H2lo, Z);    R2 = MFMA16(W4f3, H2hi, R2); \
        f32x4 D1 = A1 + R1, D2 = A2 + R2; \
        TANHPK(n2lo, n2hi, D1, D2) \
    } \
    if (DO0) { H0lo = n0lo; H0hi = n0hi; } \
    if (DO1) { H1lo = n1lo; H1hi = n1hi; } \
    if (DO2) { H2lo = n2lo; H2hi = n2hi; } \
}

// One wave per block, 16 batches, all 3 layers; zero barriers, h in registers.
__global__ __launch_bounds__(64, 1) void rnn_mfma(
    const float* __restrict__ x,
    const float* __restrict__ w_ih0,
    const float* __restrict__ b_ih0, const float* __restrict__ b_hh0,
    const float* __restrict__ b_ih1, const float* __restrict__ b_hh1,
    const float* __restrict__ b_ih2, const float* __restrict__ b_hh2,
    const float* __restrict__ fc_w,  const float* __restrict__ fc_b,
    const u32* __restrict__ wpk,
    float* __restrict__ out)
{
    __shared__ __align__(16) float xs[16][XSTR];

    const int l   = threadIdx.x;
    const int b   = l & 15;
    const int g   = l >> 4;
    const int gb0 = blockIdx.x * 16;

    // ---- stage x (coalesced float4); same-wave consumer -> no barrier ----
    for (int i = l; i < 16 * 128; i += 64) {
        int row = i >> 7, col = (i & 127) * 4;
        *(float4*)&xs[row][col] = *(const float4*)(x + (size_t)(gb0 + row) * T_LEN + col);
    }

    // ---- all 20 weight A-fragments (40 VGPR) ----
    LDF(W0f0, 0, 0) LDF(W0f1, 0, 1) LDF(W0f2, 0, 2) LDF(W0f3, 0, 3)   // whh0
    LDF(W1f0, 1, 0) LDF(W1f1, 1, 1) LDF(W1f2, 1, 2) LDF(W1f3, 1, 3)   // wih1
    LDF(W2f0, 2, 0) LDF(W2f1, 2, 1) LDF(W2f2, 2, 2) LDF(W2f3, 2, 3)   // whh1
    LDF(W3f0, 3, 0) LDF(W3f1, 3, 1) LDF(W3f2, 3, 2) LDF(W3f3, 3, 3)   // wih2
    LDF(W4f0, 4, 0) LDF(W4f1, 4, 1) LDF(W4f2, 4, 2) LDF(W4f3, 4, 3)   // whh2

    // ---- biases in D layout (tile1: j=4g+r; tile2: j=16+r on g==0) ----
    f32x4 bd01, bd02, bd11, bd12, bd21, bd22, w0lo, w0hi;
    #pragma unroll
    for (int r = 0; r < 4; ++r) {
        int j = 4 * g + r;
        bd01[r] = b_ih0[j] + b_hh0[j];
        bd11[r] = b_ih1[j] + b_hh1[j];
        bd21[r] = b_ih2[j] + b_hh2[j];
        bd02[r] = (g == 0) ? b_ih0[16 + r] + b_hh0[16 + r] : 0.f;
        bd12[r] = (g == 0) ? b_ih1[16 + r] + b_hh1[16 + r] : 0.f;
        bd22[r] = (g == 0) ? b_ih2[16 + r] + b_hh2[16 + r] : 0.f;
        w0lo[r] = w_ih0[j];
        w0hi[r] = (g == 0) ? w_ih0[16 + r] : 0.f;
    }
    const f32x4 Z = {0.f, 0.f, 0.f, 0.f};

    // ---- recurrent states in registers ----
    f16x4 H0lo = {}, H0hi = {}, H1lo = {}, H1hi = {}, H2lo = {}, H2hi = {};

    // ---- diagonal pipeline, zero barriers ----
    TICK(0, 1, 0, 0)
    TICK(1, 1, 1, 0)
    for (int s = 2; s < T_LEN; ++s) {
        TICK(s, 1, 1, 1)
    }
    TICK(0, 0, 1, 1)   // h1(511), h2(510)
    TICK(0, 0, 0, 1)   // h2(511)

    // ---- FC epilogue (R18-validated reduce) ----
    float acc = 0.f;
    #pragma unroll
    for (int i = 0; i < 4; ++i)
        acc = fmaf((float)H2lo[i], fc_w[4 * g + i], acc);
    if (g == 0) {
        #pragma unroll
        for (int i = 0; i < 4; ++i)
            acc = fmaf((float)H2hi[i], fc_w[16 + i], acc);
    }
    acc += __shfl_xor(acc, 16);
    acc += __shfl_xor(acc, 32);
    if (l < 16) out[gb0 + l] = acc + fc_b[0];
}

extern "C" void kernel_launch(void* const* d_in, const int* in_sizes, int n_in,
                              void* d_out, int out_size, void* d_ws, size_t ws_size,
                              hipStream_t stream) {
    const float* x     = (const float*)d_in[0];
    const float* w_ih0 = (const float*)d_in[1];
    const float* w_hh0 = (const float*)d_in[2];
    const float* b_ih0 = (const float*)d_in[3];
    const float* b_hh0 = (const float*)d_in[4];
    const float* w_ih1 = (const float*)d_in[5];
    const float* w_hh1 = (const float*)d_in[6];
    const float* b_ih1 = (const float*)d_in[7];
    const float* b_hh1 = (const float*)d_in[8];
    const float* w_ih2 = (const float*)d_in[9];
    const float* w_hh2 = (const float*)d_in[10];
    const float* b_ih2 = (const float*)d_in[11];
    const float* b_hh2 = (const float*)d_in[12];
    const float* fc_w  = (const float*)d_in[13];
    const float* fc_b  = (const float*)d_in[14];
    float* out = (float*)d_out;
    u32* wpk = (u32*)d_ws;   // 5 * 4 * 64 * 2 * 4 = 10240 B

    prep_w<<<1, 256, 0, stream>>>(w_hh0, w_ih1, w_hh1, w_ih2, w_hh2, wpk);

    rnn_mfma<<<B_TOTAL / 16, 64, 0, stream>>>(
        x, w_ih0, b_ih0, b_hh0, b_ih1, b_hh1, b_ih2, b_hh2,
        fc_w, fc_b, wpk, out);
}

// Round 20
// 200.384 us; speedup vs baseline: 1.5931x; 1.5931x over previous
//
#include <hip/hip_runtime.h>
#include <hip/hip_fp16.h>

// B=8192, T=512, IN=1, H=20, OUT=1
#define B_TOTAL 8192
#define T_LEN   512
#define H       20
#define KSTEP   4
#define NSUPER  (T_LEN / KSTEP)     // 128
#define CHUNK   128                 // x timesteps staged at once (32 super-ticks)
#define XSTRC   132                 // chunk row stride: 132%32=4 -> <=2-way (free)

typedef _Float16 f16x4 __attribute__((ext_vector_type(4)));
typedef float    f32x4 __attribute__((ext_vector_type(4)));
typedef unsigned int u32;

// 16x16x16 f16 MFMA (R18-validated): D lane(b,g) rows j=4g+r ; B lane(b,g)
// k=4g+i -> tanh(D)+pack IS next step's B-fragment, zero cross-lane ops.
#if defined(__HIP_DEVICE_COMPILE__)
  #if __has_builtin(__builtin_amdgcn_mfma_f32_16x16x16_f16)
    #define MFMA16(a, b, c) __builtin_amdgcn_mfma_f32_16x16x16_f16((a), (b), (c), 0, 0, 0)
  #elif __has_builtin(__builtin_amdgcn_mfma_f32_16x16x16f16)
    #define MFMA16(a, b, c) __builtin_amdgcn_mfma_f32_16x16x16f16((a), (b), (c), 0, 0, 0)
  #else
    #error "no 16x16x16 f16 MFMA builtin on device"
  #endif
#else
  #define MFMA16(a, b, c) (c)   // host parse stub
#endif

__device__ __forceinline__ float fast_tanh(float x) {
    float e = __builtin_amdgcn_exp2f(x * 2.885390081777927f);
    return fmaf(-2.0f, __builtin_amdgcn_rcpf(e + 1.0f), 1.0f);
}
__device__ __forceinline__ u32 pk2(float a, float b) {
    return __builtin_bit_cast(u32, __builtin_amdgcn_cvt_pkrtz(a, b));
}
__device__ __forceinline__ f16x4 u2f(uint2 v) { return __builtin_bit_cast(f16x4, v); }

// ---- prologue: pack 5 HxH matrices into 16x16x16 A-fragments (R18 verbatim) ----
__global__ void prep_w(const float* __restrict__ w_hh0, const float* __restrict__ w_ih1,
                       const float* __restrict__ w_hh1, const float* __restrict__ w_ih2,
                       const float* __restrict__ w_hh2, u32* __restrict__ ws)
{
    for (int e = threadIdx.x; e < 5 * 4 * 64; e += 256) {
        int l = e & 63, f = (e >> 6) & 3, m = e >> 8;
        const float* src = (m == 0) ? w_hh0 : (m == 1) ? w_ih1 :
                           (m == 2) ? w_hh1 : (m == 3) ? w_ih2 : w_hh2;
        int p = l & 15, g = l >> 4;
        int row = (f & 2) ? 16 + p : p;
        int kb  = ((f & 1) ? 16 : 0) + 4 * g;
        u32 d0 = 0, d1 = 0;
        if (row < H) {
            unsigned short h[4];
            #pragma unroll
            for (int i = 0; i < 4; ++i) {
                int k = kb + i;
                _Float16 v = (k < H) ? (_Float16)src[row * H + k] : (_Float16)0.f;
                h[i] = __builtin_bit_cast(unsigned short, v);
            }
            d0 = (u32)h[0] | ((u32)h[1] << 16);
            d1 = (u32)h[2] | ((u32)h[3] << 16);
        }
        ws[e * 2 + 0] = d0;
        ws[e * 2 + 1] = d1;
    }
}

#define LDF(name, m, f) \
    const f16x4 name = u2f(*(const uint2*)(wpk + (((m) * 4 + (f)) * 64 + l) * 2));

// tanh(D1,D2) -> packed f16 state + uint4 for LDS handoff
#define TANHPK4(lo, hi, pkd, D1, D2) { \
    u32 a0 = pk2(fast_tanh((D1)[0]), fast_tanh((D1)[1])); \
    u32 a1 = pk2(fast_tanh((D1)[2]), fast_tanh((D1)[3])); \
    u32 a2 = pk2(fast_tanh((D2)[0]), fast_tanh((D2)[1])); \
    u32 a3 = pk2(fast_tanh((D2)[2]), fast_tanh((D2)[3])); \
    lo = u2f(make_uint2(a0, a1)); \
    hi = u2f(make_uint2(a2, a3)); \
    pkd = make_uint4(a0, a1, a2, a3); \
}

// 3 waves/block (one layer each), U=2 independent 16-batch tiles per wave
// (32 batches/block). Per-step the two tiles' chains interleave in-order ->
// guaranteed intra-wave latency hiding. Numerics identical to R18.
__global__ __launch_bounds__(192, 1) void rnn_mfma(
    const float* __restrict__ x,
    const float* __restrict__ w_ih0,
    const float* __restrict__ b_ih0, const float* __restrict__ b_hh0,
    const float* __restrict__ b_ih1, const float* __restrict__ b_hh1,
    const float* __restrict__ b_ih2, const float* __restrict__ b_hh2,
    const float* __restrict__ fc_w,  const float* __restrict__ fc_b,
    const u32* __restrict__ wpk,
    float* __restrict__ out)
{
    __shared__ __align__(16) float xs[32][XSTRC];        // 128-step chunk, rows: u*16+b
    __shared__ __align__(16) uint4 h0b[2][2][KSTEP][64]; // [u][parity][s][lane]
    __shared__ __align__(16) uint4 h1b[2][2][KSTEP][64];

    const int tid = threadIdx.x;
    const int wv  = tid >> 6;
    const int l   = tid & 63;
    const int b   = l & 15;
    const int g   = l >> 4;
    const int gb0 = blockIdx.x * 32;

    // ---- stage x chunk 0 (t in [0,128)), both tiles, cooperative ----
    for (int i = tid; i < 32 * (CHUNK / 4); i += 192) {
        int row = i >> 5, col4 = i & 31;
        *(float4*)&xs[row][col4 * 4] =
            *(const float4*)(x + (size_t)(gb0 + row) * T_LEN + col4 * 4);
    }

    // ---- per-wave weight A-fragments (shared across both tiles) ----
    const int mA = (wv == 1) ? 1 : 3;
    const int mB = (wv == 0) ? 0 : (wv == 1) ? 2 : 4;
    f16x4 IAlo1 = {}, IAhi1 = {}, IAlo2 = {}, IAhi2 = {};
    if (wv != 0) {
        IAlo1 = u2f(*(const uint2*)(wpk + ((mA * 4 + 0) * 64 + l) * 2));
        IAhi1 = u2f(*(const uint2*)(wpk + ((mA * 4 + 1) * 64 + l) * 2));
        IAlo2 = u2f(*(const uint2*)(wpk + ((mA * 4 + 2) * 64 + l) * 2));
        IAhi2 = u2f(*(const uint2*)(wpk + ((mA * 4 + 3) * 64 + l) * 2));
    }
    const f16x4 RAlo1 = u2f(*(const uint2*)(wpk + ((mB * 4 + 0) * 64 + l) * 2));
    const f16x4 RAhi1 = u2f(*(const uint2*)(wpk + ((mB * 4 + 1) * 64 + l) * 2));
    const f16x4 RAlo2 = u2f(*(const uint2*)(wpk + ((mB * 4 + 2) * 64 + l) * 2));
    const f16x4 RAhi2 = u2f(*(const uint2*)(wpk + ((mB * 4 + 3) * 64 + l) * 2));

    // ---- biases in D layout ----
    const float* bi = (wv == 0) ? b_ih0 : (wv == 1) ? b_ih1 : b_ih2;
    const float* bh = (wv == 0) ? b_hh0 : (wv == 1) ? b_hh1 : b_hh2;
    f32x4 bd1, bd2, w0lo, w0hi;
    #pragma unroll
    for (int r = 0; r < 4; ++r) {
        int j = 4 * g + r;
        bd1[r]  = bi[j] + bh[j];
        bd2[r]  = (g == 0) ? bi[16 + r] + bh[16 + r] : 0.f;
        w0lo[r] = w_ih0[j];
        w0hi[r] = (g == 0) ? w_ih0[16 + r] : 0.f;
    }

    // ---- recurrent states: two tiles (A = batches 0-15, B = 16-31) ----
    f16x4 HloA = {}, HhiA = {}, HloB = {}, HhiB = {};

    for (int m = 0; m < NSUPER + 2; ++m) {
        __syncthreads();
        if (wv == 0) {
            if (m < NSUPER) {
                // restage next x chunk when crossing a 128-step boundary
                if (m > 0 && (m & 31) == 0) {
                    const int tc = (m >> 5) * CHUNK;
                    for (int i = l; i < 32 * (CHUNK / 4); i += 64) {
                        int row = i >> 5, col4 = i & 31;
                        *(float4*)&xs[row][col4 * 4] =
                            *(const float4*)(x + (size_t)(gb0 + row) * T_LEN + tc + col4 * 4);
                    }
                }
                f32x4 P1a[KSTEP], P2a[KSTEP], P1b[KSTEP], P2b[KSTEP];
                #pragma unroll
                for (int s = 0; s < KSTEP; ++s) {
                    int tl = (KSTEP * m + s) & (CHUNK - 1);
                    float xa = xs[b][tl];
                    float xb = xs[16 + b][tl];
                    #pragma unroll
                    for (int r = 0; r < 4; ++r) {
                        P1a[s][r] = fmaf(xa, w0lo[r], bd1[r]);
                        P2a[s][r] = fmaf(xa, w0hi[r], bd2[r]);
                        P1b[s][r] = fmaf(xb, w0lo[r], bd1[r]);
                        P2b[s][r] = fmaf(xb, w0hi[r], bd2[r]);
                    }
                }
                #pragma unroll
                for (int s = 0; s < KSTEP; ++s) {
                    f32x4 D1a = MFMA16(RAlo1, HloA, P1a[s]); D1a = MFMA16(RAhi1, HhiA, D1a);
                    f32x4 D2a = MFMA16(RAlo2, HloA, P2a[s]); D2a = MFMA16(RAhi2, HhiA, D2a);
                    f32x4 D1b = MFMA16(RAlo1, HloB, P1b[s]); D1b = MFMA16(RAhi1, HhiB, D1b);
                    f32x4 D2b = MFMA16(RAlo2, HloB, P2b[s]); D2b = MFMA16(RAhi2, HhiB, D2b);
                    uint4 pa, pb;
                    TANHPK4(HloA, HhiA, pa, D1a, D2a)
                    TANHPK4(HloB, HhiB, pb, D1b, D2b)
                    h0b[0][m & 1][s][l] = pa;
                    h0b[1][m & 1][s][l] = pb;
                }
            }
        } else if (wv == 1) {
            if (m >= 1 && m <= NSUPER) {
                f32x4 P1a[KSTEP], P2a[KSTEP], P1b[KSTEP], P2b[KSTEP];
                #pragma unroll
                for (int s = 0; s < KSTEP; ++s) {
                    uint4 va = h0b[0][(m - 1) & 1][s][l];
                    uint4 vb = h0b[1][(m - 1) & 1][s][l];
                    f16x4 BloA = u2f(make_uint2(va.x, va.y));
                    f16x4 BhiA = u2f(make_uint2(va.z, va.w));
                    f16x4 BloB = u2f(make_uint2(vb.x, vb.y));
                    f16x4 BhiB = u2f(make_uint2(vb.z, vb.w));
                    P1a[s] = MFMA16(IAlo1, BloA, bd1); P1a[s] = MFMA16(IAhi1, BhiA, P1a[s]);
                    P2a[s] = MFMA16(IAlo2, BloA, bd2); P2a[s] = MFMA16(IAhi2, BhiA, P2a[s]);
                    P1b[s] = MFMA16(IAlo1, BloB, bd1); P1b[s] = MFMA16(IAhi1, BhiB, P1b[s]);
                    P2b[s] = MFMA16(IAlo2, BloB, bd2); P2b[s] = MFMA16(IAhi2, BhiB, P2b[s]);
                }
                #pragma unroll
                for (int s = 0; s < KSTEP; ++s) {
                    f32x4 D1a = MFMA16(RAlo1, HloA, P1a[s]); D1a = MFMA16(RAhi1, HhiA, D1a);
                    f32x4 D2a = MFMA16(RAlo2, HloA, P2a[s]); D2a = MFMA16(RAhi2, HhiA, D2a);
                    f32x4 D1b = MFMA16(RAlo1, HloB, P1b[s]); D1b = MFMA16(RAhi1, HhiB, D1b);
                    f32x4 D2b = MFMA16(RAlo2, HloB, P2b[s]); D2b = MFMA16(RAhi2, HhiB, D2b);
                    uint4 pa, pb;
                    TANHPK4(HloA, HhiA, pa, D1a, D2a)
                    TANHPK4(HloB, HhiB, pb, D1b, D2b)
                    h1b[0][(m - 1) & 1][s][l] = pa;
                    h1b[1][(m - 1) & 1][s][l] = pb;
                }
            }
        } else {
            if (m >= 2) {
                f32x4 P1a[KSTEP], P2a[KSTEP], P1b[KSTEP], P2b[KSTEP];
                #pragma unroll
                for (int s = 0; s < KSTEP; ++s) {
                    uint4 va = h1b[0][m & 1][s][l];          // (m-2)&1 == m&1
                    uint4 vb = h1b[1][m & 1][s][l];
                    f16x4 BloA = u2f(make_uint2(va.x, va.y));
                    f16x4 BhiA = u2f(make_uint2(va.z, va.w));
                    f16x4 BloB = u2f(make_uint2(vb.x, vb.y));
                    f16x4 BhiB = u2f(make_uint2(vb.z, vb.w));
                    P1a[s] = MFMA16(IAlo1, BloA, bd1); P1a[s] = MFMA16(IAhi1, BhiA, P1a[s]);
                    P2a[s] = MFMA16(IAlo2, BloA, bd2); P2a[s] = MFMA16(IAhi2, BhiA, P2a[s]);
                    P1b[s] = MFMA16(IAlo1, BloB, bd1); P1b[s] = MFMA16(IAhi1, BhiB, P1b[s]);
                    P2b[s] = MFMA16(IAlo2, BloB, bd2); P2b[s] = MFMA16(IAhi2, BhiB, P2b[s]);
                }
                #pragma unroll
                for (int s = 0; s < KSTEP; ++s) {
                    f32x4 D1a = MFMA16(RAlo1, HloA, P1a[s]); D1a = MFMA16(RAhi1, HhiA, D1a);
                    f32x4 D2a = MFMA16(RAlo2, HloA, P2a[s]); D2a = MFMA16(RAhi2, HhiA, D2a);
                    f32x4 D1b = MFMA16(RAlo1, HloB, P1b[s]); D1b = MFMA16(RAhi1, HhiB, D1b);
                    f32x4 D2b = MFMA16(RAlo2, HloB, P2b[s]); D2b = MFMA16(RAhi2, HhiB, D2b);
                    uint4 pa, pb;
                    TANHPK4(HloA, HhiA, pa, D1a, D2a)
                    TANHPK4(HloB, HhiB, pb, D1b, D2b)
                }
            }
        }
    }

    // ---- FC epilogue: wave2 holds h2(511) for both tiles ----
    if (wv == 2) {
        float accA = 0.f, accB = 0.f;
        #pragma unroll
        for (int i = 0; i < 4; ++i) {
            accA = fmaf((float)HloA[i], fc_w[4 * g + i], accA);
            accB = fmaf((float)HloB[i], fc_w[4 * g + i], accB);
        }
        if (g == 0) {
            #pragma unroll
            for (int i = 0; i < 4; ++i) {
                accA = fmaf((float)HhiA[i], fc_w[16 + i], accA);
                accB = fmaf((float)HhiB[i], fc_w[16 + i], accB);
            }
        }
        accA += __shfl_xor(accA, 16);
        accA += __shfl_xor(accA, 32);
        accB += __shfl_xor(accB, 16);
        accB += __shfl_xor(accB, 32);
        if (l < 16) {
            out[gb0 + l]      = accA + fc_b[0];
            out[gb0 + 16 + l] = accB + fc_b[0];
        }
    }
}

extern "C" void kernel_launch(void* const* d_in, const int* in_sizes, int n_in,
                              void* d_out, int out_size, void* d_ws, size_t ws_size,
                              hipStream_t stream) {
    const float* x     = (const float*)d_in[0];
    const float* w_ih0 = (const float*)d_in[1];
    const float* w_hh0 = (const float*)d_in[2];
    const float* b_ih0 = (const float*)d_in[3];
    const float* b_hh0 = (const float*)d_in[4];
    const float* w_ih1 = (const float*)d_in[5];
    const float* w_hh1 = (const float*)d_in[6];
    const float* b_ih1 = (const float*)d_in[7];
    const float* b_hh1 = (const float*)d_in[8];
    const float* w_ih2 = (const float*)d_in[9];
    const float* w_hh2 = (const float*)d_in[10];
    const float* b_ih2 = (const float*)d_in[11];
    const float* b_hh2 = (const float*)d_in[12];
    const float* fc_w  = (const float*)d_in[13];
    const float* fc_b  = (const float*)d_in[14];
    float* out = (float*)d_out;
    u32* wpk = (u32*)d_ws;   // 5 * 4 * 64 * 2 * 4 = 10240 B

    prep_w<<<1, 256, 0, stream>>>(w_hh0, w_ih1, w_hh1, w_ih2, w_hh2, wpk);

    rnn_mfma<<<B_TOTAL / 32, 192, 0, stream>>>(
        x, w_ih0, b_ih0, b_hh0, b_ih1, b_hh1, b_ih2, b_hh2,
        fc_w, fc_b, wpk, out);
}